// Round 2
// baseline (4834.051 us; speedup 1.0000x reference)
//
#include <hip/hip_runtime.h>
#include <hip/hip_bf16.h>

// CGCNN forward, MI355X — Gram-stat formulation (no stats pass over edges):
//   BN1 stats: mean = sW/NE, E[z^2] = W^T G W / NE with G assembled from
//   node-scale pieces (H = CSR neighbor-sum, F1/F2 = CSR ef-sums, ef^Tef once).
//   Edge pass: CSR(idx1)-ordered MFMA GEMM -> BN -> sigmoid*softplus ->
//   register run-length reduce -> few atomics.

#define NN 100000
#define NE 1600000
#define NC 2000
#define KPAD 192
#define EPSB 1e-5f
#define NCH 1000
#define CH 100

typedef _Float16 f16;
typedef _Float16 half8 __attribute__((ext_vector_type(8)));
typedef float f32x16 __attribute__((ext_vector_type(16)));

__device__ __forceinline__ f32x16 zero16() {
    f32x16 v;
#pragma unroll
    for (int i = 0; i < 16; i++) v[i] = 0.f;
    return v;
}
__device__ __forceinline__ float softplus_f(float x) {
    return fmaxf(x, 0.f) + log1pf(expf(-fabsf(x)));
}
__device__ __forceinline__ float sigmoid_f(float x) {
    return 1.f / (1.f + expf(-x));
}

// ---------- prep ----------
__global__ void k_prep_x(const int* __restrict__ nf, const float* __restrict__ emb,
                         float* __restrict__ xf, f16* __restrict__ x16) {
    for (int idx = blockIdx.x * blockDim.x + threadIdx.x; idx < NN * 64;
         idx += gridDim.x * blockDim.x) {
        int n = idx >> 6, k = idx & 63;
        float v = emb[nf[n] * 64 + k];
        xf[idx] = v;
        x16[idx] = (f16)v;
    }
}

__global__ void k_prep_ef(const float* __restrict__ ef, f16* __restrict__ ef16) {
    for (long idx = blockIdx.x * blockDim.x + threadIdx.x; idx < (long)NE * 64;
         idx += (long)gridDim.x * blockDim.x) {
        long e = idx >> 6;
        int k = (int)(idx & 63);
        float v = (k < 41) ? ef[e * 41 + k] : 0.f;
        ef16[idx] = (f16)v;
    }
}

__global__ void k_deg(const int* __restrict__ idx1, const int* __restrict__ idx2,
                      const int* __restrict__ idx3, int* deg1, int* deg2, float* cnt3) {
    for (int i = blockIdx.x * blockDim.x + threadIdx.x; i < NE;
         i += gridDim.x * blockDim.x) {
        atomicAdd(&deg1[idx1[i]], 1);
        atomicAdd(&deg2[idx2[i]], 1);
        if (i < NN) atomicAdd(&cnt3[idx3[i]], 1.f);
    }
}

// ---------- scan (exclusive prefix of deg -> row_ptr) ----------
__global__ void k_scan_a(const int* __restrict__ deg, int* __restrict__ csum) {
    int t = blockIdx.x * blockDim.x + threadIdx.x;
    if (t < NCH) {
        int s = 0;
        int base = t * CH;
        for (int i = 0; i < CH; i++) s += deg[base + i];
        csum[t] = s;
    }
}
__global__ void k_scan_b(const int* __restrict__ csum, int* __restrict__ coff) {
    __shared__ int sc[256];
    int t = threadIdx.x;
    int v[4];
    int part = 0;
#pragma unroll
    for (int q = 0; q < 4; q++) {
        int idx = 4 * t + q;
        v[q] = (idx < NCH) ? csum[idx] : 0;
        part += v[q];
    }
    sc[t] = part;
    __syncthreads();
    for (int off = 1; off < 256; off <<= 1) {
        int add = (t >= off) ? sc[t - off] : 0;
        __syncthreads();
        sc[t] += add;
        __syncthreads();
    }
    int run = sc[t] - part;  // exclusive
#pragma unroll
    for (int q = 0; q < 4; q++) {
        int idx = 4 * t + q;
        if (idx < NCH) coff[idx] = run;
        run += v[q];
    }
}
__global__ void k_scan_c(const int* __restrict__ deg, const int* __restrict__ coff,
                         int* __restrict__ rp) {
    int t = blockIdx.x * blockDim.x + threadIdx.x;
    if (t < NCH) {
        int running = coff[t];
        int base = t * CH;
        for (int i = 0; i < CH; i++) {
            rp[base + i] = running;
            running += deg[base + i];
        }
    }
}

__global__ void k_scatter(const int* __restrict__ idx1, const int* __restrict__ idx2,
                          const int* __restrict__ rp1, const int* __restrict__ rp2,
                          int* cur1, int* cur2, int* elist1, int* elist2,
                          int* i1r, int* i2r) {
    for (int e = blockIdx.x * blockDim.x + threadIdx.x; e < NE;
         e += gridDim.x * blockDim.x) {
        int n1 = idx1[e];
        int p = rp1[n1] + atomicAdd(&cur1[n1], 1);
        elist1[p] = e;
        i1r[p] = n1;
        i2r[p] = idx2[e];
        int n2 = idx2[e];
        int p2 = rp2[n2] + atomicAdd(&cur2[n2], 1);
        elist2[p2] = e;
    }
}

// gather-sum rows of src (64-wide f16) per CSR bucket: out[n] = sum src[idxarr[p]]
__global__ __launch_bounds__(256) void k_bucket_sum(
    const f16* __restrict__ src, const int* __restrict__ rp, const int* __restrict__ deg,
    const int* __restrict__ idxarr, f16* __restrict__ out) {
    int tid = threadIdx.x;
    int lane = tid & 63, wv = tid >> 6;
    for (int n = blockIdx.x * 4 + wv; n < NN; n += gridDim.x * 4) {
        int start = rp[n], d = deg[n];
        float acc = 0.f;
        for (int q = 0; q < d; q++) {
            int row = idxarr[start + q];
            acc += (float)src[(size_t)row * 64 + lane];
        }
        out[(size_t)n * 64 + lane] = (f16)acc;
    }
}

// ---------- gram: out(64x64) += P^T Q over `rows` 64-wide f16 rows ----------
__global__ __launch_bounds__(256) void k_gram(const f16* __restrict__ P,
                                              const f16* __restrict__ Q,
                                              const int* __restrict__ wdeg, long rows,
                                              int onescol, int same,
                                              float* __restrict__ out) {
    __shared__ f16 PT[64 * 72];
    __shared__ f16 QT[64 * 72];
    int tid = threadIdx.x;
    int lane = tid & 63, wv = tid >> 6;
    int c = lane & 31, kg = lane >> 5;
    int r = tid >> 2, seg = (tid & 3) * 16;
    f32x16 acc = zero16();
    long ntiles = (rows + 63) >> 6;
    for (long tile = blockIdx.x; tile < ntiles; tile += gridDim.x) {
        long grow = tile * 64 + r;
        bool valid = grow < rows;
        float w = 1.f;
        if (wdeg && valid) w = (float)wdeg[grow];
        half8 h0, h1;
#pragma unroll
        for (int i = 0; i < 8; i++) { h0[i] = (f16)0.f; h1[i] = (f16)0.f; }
        if (valid) {
            h0 = *(const half8*)(P + grow * 64 + seg);
            h1 = *(const half8*)(P + grow * 64 + seg + 8);
        }
#pragma unroll
        for (int i = 0; i < 8; i++) {
            PT[(seg + i) * 72 + r] = (f16)((float)h0[i] * w);
            PT[(seg + 8 + i) * 72 + r] = (f16)((float)h1[i] * w);
        }
        if (onescol >= seg && onescol < seg + 16) PT[onescol * 72 + r] = (f16)1.f;
        if (!same) {
            half8 q0, q1;
#pragma unroll
            for (int i = 0; i < 8; i++) { q0[i] = (f16)0.f; q1[i] = (f16)0.f; }
            if (valid) {
                q0 = *(const half8*)(Q + grow * 64 + seg);
                q1 = *(const half8*)(Q + grow * 64 + seg + 8);
            }
#pragma unroll
            for (int i = 0; i < 8; i++) {
                QT[(seg + i) * 72 + r] = q0[i];
                QT[(seg + 8 + i) * 72 + r] = q1[i];
            }
        }
        __syncthreads();
        int mrow = (wv >> 1) * 32 + c;
        int ncol = (wv & 1) * 32 + c;
#pragma unroll
        for (int ks = 0; ks < 4; ks++) {
            half8 af = *(const half8*)&PT[mrow * 72 + ks * 16 + kg * 8];
            half8 bf = same ? *(const half8*)&PT[ncol * 72 + ks * 16 + kg * 8]
                            : *(const half8*)&QT[ncol * 72 + ks * 16 + kg * 8];
            acc = __builtin_amdgcn_mfma_f32_32x32x16_f16(af, bf, acc, 0, 0, 0);
        }
        __syncthreads();
    }
#pragma unroll
    for (int reg = 0; reg < 16; reg++) {
        int row = (reg & 3) + 8 * (reg >> 2) + 4 * kg;
        atomicAdd(&out[(size_t)((wv >> 1) * 32 + row) * 64 + (wv & 1) * 32 + c],
                  acc[reg]);
    }
}

// weighted column sums: sbuf[j] += sum deg1[n]*x[n,j]; sbuf[64+j] += deg2-weighted
__global__ __launch_bounds__(256) void k_colsum(const f16* __restrict__ x16,
                                                const int* __restrict__ deg1,
                                                const int* __restrict__ deg2,
                                                float* __restrict__ sbuf) {
    __shared__ float sh[256];
    int tid = threadIdx.x;
    int j = tid & 63, rl = tid >> 6;
    float p1 = 0.f, p2 = 0.f;
    for (int n = blockIdx.x * 4 + rl; n < NN; n += gridDim.x * 4) {
        float v = (float)x16[(size_t)n * 64 + j];
        p1 += (float)deg1[n] * v;
        p2 += (float)deg2[n] * v;
    }
    sh[tid] = p1;
    __syncthreads();
    if (tid < 64) atomicAdd(&sbuf[tid], sh[tid] + sh[tid + 64] + sh[tid + 128] + sh[tid + 192]);
    __syncthreads();
    sh[tid] = p2;
    __syncthreads();
    if (tid < 64) atomicAdd(&sbuf[64 + tid], sh[tid] + sh[tid + 64] + sh[tid + 128] + sh[tid + 192]);
}

// BN1 coefficients from Gram pieces. 128 blocks (one per col), 192 threads.
__global__ void k_bn_coef(const float* __restrict__ Wf_l, const float* __restrict__ sbuf,
                          const float* __restrict__ g11, const float* __restrict__ g12,
                          const float* __restrict__ g22, const float* __restrict__ gF1,
                          const float* __restrict__ gF2, const float* __restrict__ gee,
                          const float* __restrict__ gamma, const float* __restrict__ beta,
                          float* __restrict__ aC, float* __restrict__ bC) {
    __shared__ float wl[192];
    __shared__ double red[192];
    __shared__ double red2[192];
    int c = blockIdx.x;
    int k = threadIdx.x;
    float wk = 0.f;
    if (k < 169) wk = (float)(f16)Wf_l[k * 128 + c];  // quantize to match WTp
    wl[k] = wk;
    __syncthreads();
    int bk = k >> 6, rk = k & 63;
    double t = 0.0;
    const float *r0, *r1, *r2;
    bool t0 = false, t1 = false;
    if (bk == 0) { r0 = g11 + rk * 64; r1 = g12 + rk * 64; r2 = gF1 + rk * 64; }
    else if (bk == 1) { r0 = g12; t0 = true; r1 = g22 + rk * 64; r2 = gF2 + rk * 64; }
    else { r0 = gF1; t0 = true; r1 = gF2; t1 = true; r2 = gee + rk * 64; }
    for (int j = 0; j < 64; j++) t += (double)(t0 ? r0[j * 64 + rk] : r0[j]) * wl[j];
    for (int j = 0; j < 64; j++) t += (double)(t1 ? r1[j * 64 + rk] : r1[j]) * wl[64 + j];
    for (int j = 0; j < 64; j++) t += (double)r2[j] * wl[128 + j];
    double sk = (k < 128) ? (double)sbuf[k] : (double)gee[41 * 64 + (k - 128)];
    red[k] = (double)wl[k] * t;
    red2[k] = (double)wl[k] * sk;
    __syncthreads();
    if (k == 0) {
        double q = 0.0, sm = 0.0;
        for (int i = 0; i < 192; i++) { q += red[i]; sm += red2[i]; }
        double mean = sm / NE;
        double var = q / NE - mean * mean;
        float a = gamma[c] * rsqrtf((float)var + EPSB);
        aC[c] = a;
        bC[c] = beta[c] - (float)mean * a;
    }
}

// WTp: col-permuted W^T (f16, KPAD rows). slot sl -> actual col pairs gate/conv.
__global__ void k_wt(const float* __restrict__ Wf_l, f16* __restrict__ WTp) {
    for (int idx = blockIdx.x * blockDim.x + threadIdx.x; idx < 128 * KPAD;
         idx += gridDim.x * blockDim.x) {
        int sl = idx / KPAD, k = idx % KPAD;
        int c = sl & 31, cw = sl >> 5;
        int base = cw * 16 + (c & 15);
        int col = (c & 16) ? 64 + base : base;
        float v = (k < 169) ? Wf_l[k * 128 + col] : 0.f;
        WTp[idx] = (f16)v;
    }
}

// ---------- main edge pass: GEMM -> BN -> msg -> run-reduced scatter ----------
__global__ __launch_bounds__(256, 4) void k_msg(
    const f16* __restrict__ x16, const f16* __restrict__ ef16,
    const f16* __restrict__ WTp, const int* __restrict__ elist,
    const int* __restrict__ i1r, const int* __restrict__ i2r,
    const float* __restrict__ aC, const float* __restrict__ bC,
    float* __restrict__ nodesum) {
    int tid = threadIdx.x;
    int lane = tid & 63;
    int cw = tid >> 6;
    int c = lane & 31, kg = lane >> 5;
    int base = cw * 16 + (c & 15);
    int jz = (c & 16) ? 64 + base : base;
    float aCv = aC[jz], bCv = bC[jz];
    half8 bfr[12];
    {
        int sl = cw * 32 + c;
        const f16* bp = WTp + sl * KPAD + kg * 8;
#pragma unroll
        for (int s = 0; s < 12; s++) bfr[s] = *(const half8*)(bp + s * 16);
    }
    bool emitter = (c < 16);
    const int NT = NE / 32;
    for (int tile = blockIdx.x; tile < NT; tile += gridDim.x) {
        int p = tile * 32 + c;
        int e = elist[p];
        int i1 = i1r[p];
        int i2 = i2r[p];
        f32x16 acc = zero16();
#pragma unroll
        for (int s = 0; s < 4; s++) {
            half8 a = *(const half8*)(x16 + (size_t)i1 * 64 + s * 16 + kg * 8);
            acc = __builtin_amdgcn_mfma_f32_32x32x16_f16(a, bfr[s], acc, 0, 0, 0);
        }
#pragma unroll
        for (int s = 0; s < 4; s++) {
            half8 a = *(const half8*)(x16 + (size_t)i2 * 64 + s * 16 + kg * 8);
            acc = __builtin_amdgcn_mfma_f32_32x32x16_f16(a, bfr[4 + s], acc, 0, 0, 0);
        }
#pragma unroll
        for (int s = 0; s < 4; s++) {
            half8 a = *(const half8*)(ef16 + (size_t)e * 64 + s * 16 + kg * 8);
            acc = __builtin_amdgcn_mfma_f32_32x32x16_f16(a, bfr[8 + s], acc, 0, 0, 0);
        }
        float accm = 0.f;
        int curn = -1;
#pragma unroll
        for (int r = 0; r < 16; r++) {
            int row = (r & 3) + 8 * (r >> 2) + 4 * kg;
            int nrow = __shfl(i1, row, 64);
            float val = acc[r] * aCv + bCv;
            float tv = (c & 16) ? softplus_f(val) : sigmoid_f(val);
            float other = __shfl_xor(tv, 16, 64);
            float m = tv * other;
            if (r == 0) {
                accm = m;
                curn = nrow;
            } else if (nrow == curn) {
                accm += m;
            } else {
                if (emitter) atomicAdd(&nodesum[(size_t)curn * 64 + base], accm);
                accm = m;
                curn = nrow;
            }
        }
        if (emitter) atomicAdd(&nodesum[(size_t)curn * 64 + base], accm);
    }
}

// ---------- node update ----------
__global__ __launch_bounds__(256) void k_node_stats(const float* __restrict__ nodesum,
                                                    const int* __restrict__ deg1,
                                                    float* __restrict__ nstats) {
    __shared__ float lst[128];
    int tid = threadIdx.x;
    if (tid < 128) lst[tid] = 0.f;
    __syncthreads();
    int j = tid & 63;
    float p1 = 0.f, p2 = 0.f;
    for (int idx = blockIdx.x * 256 + tid; idx < NN * 64; idx += gridDim.x * 256) {
        int n = idx >> 6;
        float raw = nodesum[idx] / fmaxf((float)deg1[n], 1.f);
        p1 += raw;
        p2 += raw * raw;
    }
    atomicAdd(&lst[j], p1);
    atomicAdd(&lst[64 + j], p2);
    __syncthreads();
    if (tid < 128) atomicAdd(&nstats[tid], lst[tid]);
}

__global__ __launch_bounds__(256) void k_node_apply(
    const float* __restrict__ nodesum, const int* __restrict__ deg1,
    const float* __restrict__ nstats, const float* __restrict__ g2,
    const float* __restrict__ be2, float* __restrict__ xf, f16* __restrict__ x16) {
    for (int idx = blockIdx.x * blockDim.x + threadIdx.x; idx < NN * 64;
         idx += gridDim.x * blockDim.x) {
        int n = idx >> 6, j = idx & 63;
        float m = nstats[j] * (1.f / NN);
        float var = nstats[64 + j] * (1.f / NN) - m * m;
        float rs = rsqrtf(var + EPSB);
        float a = g2[j] * rs;
        float b = be2[j] - m * a;
        float raw = nodesum[idx] / fmaxf((float)deg1[n], 1.f);
        float v = softplus_f(xf[idx] + raw * a + b);
        xf[idx] = v;
        x16[idx] = (f16)v;
    }
}

// ---------- crystal pooling + MLP ----------
__global__ void k_cry(const float* __restrict__ xf, const int* __restrict__ idx3,
                      float* __restrict__ crsum) {
    for (int idx = blockIdx.x * blockDim.x + threadIdx.x; idx < NN * 64;
         idx += gridDim.x * blockDim.x) {
        int n = idx >> 6, j = idx & 63;
        atomicAdd(&crsum[idx3[n] * 64 + j], xf[idx]);
    }
}

__global__ __launch_bounds__(128) void k_out(const float* __restrict__ crsum,
                                             const float* __restrict__ cnt3,
                                             const float* __restrict__ Wc,
                                             const float* __restrict__ bcv,
                                             const float* __restrict__ Wo,
                                             const float* __restrict__ bo,
                                             float* __restrict__ out) {
    __shared__ float crym[64];
    __shared__ float red[4];
    int c = blockIdx.x, tid = threadIdx.x;
    if (tid < 64) crym[tid] = crsum[c * 64 + tid] / fmaxf(cnt3[c], 1.f);
    __syncthreads();
    float hv = bcv[tid];
#pragma unroll
    for (int k = 0; k < 64; k++) hv += crym[k] * Wc[k * 128 + tid];
    hv = softplus_f(hv);
    float o0 = hv * Wo[tid * 2 + 0];
    float o1 = hv * Wo[tid * 2 + 1];
#pragma unroll
    for (int off = 32; off > 0; off >>= 1) {
        o0 += __shfl_down(o0, off, 64);
        o1 += __shfl_down(o1, off, 64);
    }
    int wv = tid >> 6;
    if ((tid & 63) == 0) { red[wv * 2] = o0; red[wv * 2 + 1] = o1; }
    __syncthreads();
    if (tid == 0) {
        out[c * 2 + 0] = red[0] + red[2] + bo[0];
        out[c * 2 + 1] = red[1] + red[3] + bo[1];
    }
}

// ---------- launch ----------
static inline size_t al256(size_t x) { return (x + 255) & ~(size_t)255; }

extern "C" void kernel_launch(void* const* d_in, const int* in_sizes, int n_in,
                              void* d_out, int out_size, void* d_ws, size_t ws_size,
                              hipStream_t stream) {
    const int* node_fea = (const int*)d_in[0];
    const float* edge_fea = (const float*)d_in[1];
    const int* idx1 = (const int*)d_in[2];
    const int* idx2 = (const int*)d_in[3];
    const int* idx3 = (const int*)d_in[4];
    const float* emb = (const float*)d_in[5];
    const float* Wf = (const float*)d_in[6];
    // d_in[7] = bf: cancels in training-mode BN.
    const float* g1 = (const float*)d_in[8];
    const float* be1 = (const float*)d_in[9];
    const float* g2 = (const float*)d_in[10];
    const float* be2 = (const float*)d_in[11];
    const float* Wc = (const float*)d_in[12];
    const float* bc = (const float*)d_in[13];
    const float* Wo = (const float*)d_in[14];
    const float* bo = (const float*)d_in[15];
    float* out = (float*)d_out;
    unsigned char* ws = (unsigned char*)d_ws;

    size_t off = 0;
    size_t o_xf = off;     off = al256(off + (size_t)NN * 64 * 4);
    size_t o_x16 = off;    off = al256(off + (size_t)NN * 64 * 2);
    size_t o_ef16 = off;   off = al256(off + (size_t)NE * 64 * 2);
    size_t o_WTp = off;    off = al256(off + (size_t)128 * KPAD * 2);
    size_t o_F1 = off;     off = al256(off + (size_t)NN * 64 * 2);
    size_t o_F2 = off;     off = al256(off + (size_t)NN * 64 * 2);
    size_t o_H = off;      off = al256(off + (size_t)NN * 64 * 2);
    size_t o_rp1 = off;    off = al256(off + (size_t)NN * 4);
    size_t o_rp2 = off;    off = al256(off + (size_t)NN * 4);
    size_t o_el1 = off;    off = al256(off + (size_t)NE * 4);
    size_t o_el2 = off;    off = al256(off + (size_t)NE * 4);
    size_t o_i1r = off;    off = al256(off + (size_t)NE * 4);
    size_t o_i2r = off;    off = al256(off + (size_t)NE * 4);
    size_t o_aC = off;     off = al256(off + 128 * 4);
    size_t o_bC = off;     off = al256(off + 128 * 4);
    // prep-zero region (one memset):
    size_t o_deg1 = off;   off = al256(off + (size_t)NN * 4);
    size_t o_deg2 = off;   off = al256(off + (size_t)NN * 4);
    size_t o_cur1 = off;   off = al256(off + (size_t)NN * 4);
    size_t o_cur2 = off;   off = al256(off + (size_t)NN * 4);
    size_t o_cnt3 = off;   off = al256(off + (size_t)NC * 4);
    size_t o_csum = off;   off = al256(off + 1024 * 4);
    size_t o_coff = off;   off = al256(off + 1024 * 4);
    size_t o_gee = off;    off = al256(off + 4096 * 4);
    size_t o_crsum = off;  off = al256(off + (size_t)NC * 64 * 4);
    size_t prep_zero_end = off;
    // per-layer-zero region (one memset per layer):
    size_t o_nodesum = off; off = al256(off + (size_t)NN * 64 * 4);
    size_t o_g11 = off;    off = al256(off + 4096 * 4);
    size_t o_g12 = off;    off = al256(off + 4096 * 4);
    size_t o_g22 = off;    off = al256(off + 4096 * 4);
    size_t o_gF1 = off;    off = al256(off + 4096 * 4);
    size_t o_gF2 = off;    off = al256(off + 4096 * 4);
    size_t o_sbuf = off;   off = al256(off + 128 * 4);
    size_t o_nstats = off; off = al256(off + 128 * 4);
    size_t layer_zero_end = off;

    float* xf = (float*)(ws + o_xf);
    f16* x16 = (f16*)(ws + o_x16);
    f16* ef16 = (f16*)(ws + o_ef16);
    f16* WTp = (f16*)(ws + o_WTp);
    f16* F1 = (f16*)(ws + o_F1);
    f16* F2 = (f16*)(ws + o_F2);
    f16* H16 = (f16*)(ws + o_H);
    int* rp1 = (int*)(ws + o_rp1);
    int* rp2 = (int*)(ws + o_rp2);
    int* elist1 = (int*)(ws + o_el1);
    int* elist2 = (int*)(ws + o_el2);
    int* i1r = (int*)(ws + o_i1r);
    int* i2r = (int*)(ws + o_i2r);
    float* aC = (float*)(ws + o_aC);
    float* bC = (float*)(ws + o_bC);
    int* deg1 = (int*)(ws + o_deg1);
    int* deg2 = (int*)(ws + o_deg2);
    int* cur1 = (int*)(ws + o_cur1);
    int* cur2 = (int*)(ws + o_cur2);
    float* cnt3 = (float*)(ws + o_cnt3);
    int* csum = (int*)(ws + o_csum);
    int* coff = (int*)(ws + o_coff);
    float* gee = (float*)(ws + o_gee);
    float* crsum = (float*)(ws + o_crsum);
    float* nodesum = (float*)(ws + o_nodesum);
    float* g11 = (float*)(ws + o_g11);
    float* g12 = (float*)(ws + o_g12);
    float* g22 = (float*)(ws + o_g22);
    float* gF1 = (float*)(ws + o_gF1);
    float* gF2 = (float*)(ws + o_gF2);
    float* sbuf = (float*)(ws + o_sbuf);
    float* nstats = (float*)(ws + o_nstats);

    // ---- prep ----
    hipMemsetAsync(ws + o_deg1, 0, prep_zero_end - o_deg1, stream);
    k_prep_x<<<1024, 256, 0, stream>>>(node_fea, emb, xf, x16);
    k_prep_ef<<<4096, 256, 0, stream>>>(edge_fea, ef16);
    k_deg<<<2048, 256, 0, stream>>>(idx1, idx2, idx3, deg1, deg2, cnt3);
    k_scan_a<<<4, 256, 0, stream>>>(deg1, csum);
    k_scan_b<<<1, 256, 0, stream>>>(csum, coff);
    k_scan_c<<<4, 256, 0, stream>>>(deg1, coff, rp1);
    k_scan_a<<<4, 256, 0, stream>>>(deg2, csum);
    k_scan_b<<<1, 256, 0, stream>>>(csum, coff);
    k_scan_c<<<4, 256, 0, stream>>>(deg2, coff, rp2);
    k_scatter<<<2048, 256, 0, stream>>>(idx1, idx2, rp1, rp2, cur1, cur2, elist1,
                                        elist2, i1r, i2r);
    k_bucket_sum<<<2048, 256, 0, stream>>>(ef16, rp1, deg1, elist1, F1);
    k_bucket_sum<<<2048, 256, 0, stream>>>(ef16, rp2, deg2, elist2, F2);
    // ef^T ef (+ones col 41 -> row 41 holds sum(ef))
    k_gram<<<1024, 256, 0, stream>>>(ef16, ef16, nullptr, (long)NE, 41, 1, gee);

    for (int l = 0; l < 3; l++) {
        const float* Wf_l = Wf + (size_t)l * 169 * 128;
        hipMemsetAsync(ws + o_nodesum, 0, layer_zero_end - o_nodesum, stream);
        k_wt<<<96, 256, 0, stream>>>(Wf_l, WTp);
        k_colsum<<<256, 256, 0, stream>>>(x16, deg1, deg2, sbuf);
        k_bucket_sum<<<2048, 256, 0, stream>>>(x16, rp1, deg1, i2r, H16);  // H = neighbor sums
        k_gram<<<512, 256, 0, stream>>>(x16, H16, nullptr, (long)NN, -1, 0, g12);
        k_gram<<<512, 256, 0, stream>>>(x16, x16, deg1, (long)NN, -1, 0, g11);
        k_gram<<<512, 256, 0, stream>>>(x16, x16, deg2, (long)NN, -1, 0, g22);
        k_gram<<<512, 256, 0, stream>>>(x16, F1, nullptr, (long)NN, -1, 0, gF1);
        k_gram<<<512, 256, 0, stream>>>(x16, F2, nullptr, (long)NN, -1, 0, gF2);
        k_bn_coef<<<128, 192, 0, stream>>>(Wf_l, sbuf, g11, g12, g22, gF1, gF2, gee,
                                           g1 + l * 128, be1 + l * 128, aC, bC);
        k_msg<<<1024, 256, 0, stream>>>(x16, ef16, WTp, elist1, i1r, i2r, aC, bC,
                                        nodesum);
        k_node_stats<<<1024, 256, 0, stream>>>(nodesum, deg1, nstats);
        k_node_apply<<<1024, 256, 0, stream>>>(nodesum, deg1, nstats, g2 + l * 64,
                                               be2 + l * 64, xf, x16);
    }
    k_cry<<<1024, 256, 0, stream>>>(xf, idx3, crsum);
    k_out<<<2000, 128, 0, stream>>>(crsum, cnt3, Wc, bc, Wo, bo, out);
}

// Round 3
// 2377.024 us; speedup vs baseline: 2.0337x; 2.0337x over previous
//
#include <hip/hip_runtime.h>
#include <hip/hip_bf16.h>

// CGCNN forward, MI355X. R2: R0 two-pass skeleton + HW transcendentals +
// pair-packed z buffer so pass B is a lean streaming kernel.
//   x = emb[node_fea]  (f32 + f16 copy)
//   3x: pass A: z = [x[i1]|x[i2]|ef] @ Wf[l] (f16 MFMA, fp32 acc; bf cancels
//              in train-mode BN) + column sum/sumsq + store z pairs (f16x2)
//       pass B: stream z -> BN -> sigmoid*softplus -> atomicAdd nodesum
//       node: seg-mean -> BN -> softplus -> new x
//   crystal seg-mean -> softplus(@Wc+bc) -> @Wo+bo

#define NN 100000
#define NE 1600000
#define NC 2000
#define KPAD 192
#define EPSB 1e-5f

typedef _Float16 f16;
typedef _Float16 half8 __attribute__((ext_vector_type(8)));
typedef _Float16 half2v __attribute__((ext_vector_type(2)));
typedef float f32x16 __attribute__((ext_vector_type(16)));

__device__ __forceinline__ f32x16 zero16() {
    f32x16 v;
#pragma unroll
    for (int i = 0; i < 16; i++) v[i] = 0.f;
    return v;
}
// fast transcendentals: v_exp/v_log/v_rcp based (libm expf/log1pf are ~30-instr
// OCML calls without -ffast-math; they made R0/R1 VALU-bound at ~100% VALUBusy)
__device__ __forceinline__ float fsoftplus(float x) {
    return fmaxf(x, 0.f) + __logf(1.f + __expf(-fabsf(x)));
}
__device__ __forceinline__ float fsigmoid(float x) {
    return __fdividef(1.f, 1.f + __expf(-x));
}

// ---------- prep ----------
__global__ void k_prep_x(const int* __restrict__ nf, const float* __restrict__ emb,
                         float* __restrict__ xf, f16* __restrict__ x16) {
    for (int idx = blockIdx.x * blockDim.x + threadIdx.x; idx < NN * 64;
         idx += gridDim.x * blockDim.x) {
        int n = idx >> 6, k = idx & 63;
        float v = emb[nf[n] * 64 + k];
        xf[idx] = v;
        x16[idx] = (f16)v;
    }
}

__global__ void k_prep_ef(const float* __restrict__ ef, f16* __restrict__ ef16) {
    for (long idx = blockIdx.x * blockDim.x + threadIdx.x; idx < (long)NE * 64;
         idx += (long)gridDim.x * blockDim.x) {
        long e = idx >> 6;
        int k = (int)(idx & 63);
        float v = (k < 41) ? ef[e * 41 + k] : 0.f;
        ef16[idx] = (f16)v;
    }
}

__global__ void k_cnt(const int* __restrict__ idx1, const int* __restrict__ idx3,
                      float* cnt1, float* cnt3) {
    for (int i = blockIdx.x * blockDim.x + threadIdx.x; i < NE;
         i += gridDim.x * blockDim.x) {
        atomicAdd(&cnt1[idx1[i]], 1.f);
        if (i < NN) atomicAdd(&cnt3[idx3[i]], 1.f);
    }
}

// WT[col][k] = Wf_l[k][col] (f16, k padded 169->192)
__global__ void k_wt(const float* __restrict__ Wf_l, f16* __restrict__ WT) {
    for (int idx = blockIdx.x * blockDim.x + threadIdx.x; idx < 128 * KPAD;
         idx += gridDim.x * blockDim.x) {
        int col = idx / KPAD, k = idx % KPAD;
        float v = (k < 169) ? Wf_l[k * 128 + col] : 0.f;
        WT[idx] = (f16)v;
    }
}

// ---------- edge GEMM core ----------
__device__ __forceinline__ void edge_mfma(const f16* __restrict__ x16,
                                          const f16* __restrict__ ef16,
                                          const half8 bfr[2][12], int i1, int i2,
                                          long e, int kg, f32x16& acc0, f32x16& acc1) {
    acc0 = zero16();
    acc1 = zero16();
#pragma unroll
    for (int s = 0; s < 4; s++) {
        half8 a = *reinterpret_cast<const half8*>(x16 + (long)i1 * 64 + s * 16 + kg * 8);
        acc0 = __builtin_amdgcn_mfma_f32_32x32x16_f16(a, bfr[0][s], acc0, 0, 0, 0);
        acc1 = __builtin_amdgcn_mfma_f32_32x32x16_f16(a, bfr[1][s], acc1, 0, 0, 0);
    }
#pragma unroll
    for (int s = 0; s < 4; s++) {
        half8 a = *reinterpret_cast<const half8*>(x16 + (long)i2 * 64 + s * 16 + kg * 8);
        acc0 = __builtin_amdgcn_mfma_f32_32x32x16_f16(a, bfr[0][4 + s], acc0, 0, 0, 0);
        acc1 = __builtin_amdgcn_mfma_f32_32x32x16_f16(a, bfr[1][4 + s], acc1, 0, 0, 0);
    }
#pragma unroll
    for (int s = 0; s < 4; s++) {
        half8 a = *reinterpret_cast<const half8*>(ef16 + e * 64 + s * 16 + kg * 8);
        acc0 = __builtin_amdgcn_mfma_f32_32x32x16_f16(a, bfr[0][8 + s], acc0, 0, 0, 0);
        acc1 = __builtin_amdgcn_mfma_f32_32x32x16_f16(a, bfr[1][8 + s], acc1, 0, 0, 0);
    }
}

__device__ __forceinline__ void load_bfr(const f16* __restrict__ WT, int ch, int c,
                                         int kg, half8 bfr[2][12]) {
#pragma unroll
    for (int t = 0; t < 2; t++) {
        int col = 32 * ch + 64 * t + c;
        const f16* bp = WT + col * KPAD + kg * 8;
#pragma unroll
        for (int s = 0; s < 12; s++)
            bfr[t][s] = *reinterpret_cast<const half8*>(bp + s * 16);
    }
}

// pass A: compute z, accumulate column sum/sumsq, store z pairs (f16x2)
template <bool STORE_Z>
__global__ __launch_bounds__(256) void k_edge_a(
    const f16* __restrict__ x16, const f16* __restrict__ ef16,
    const f16* __restrict__ WT, const int* __restrict__ idx1,
    const int* __restrict__ idx2, float* __restrict__ estats,
    half2v* __restrict__ zp) {
    __shared__ float lst[256];
    int tid = threadIdx.x;
    int lane = tid & 63;
    int w = tid >> 6;
    int h = w >> 1, ch = w & 1;
    int c = lane & 31, kg = lane >> 5;

    half8 bfr[2][12];
    load_bfr(WT, ch, c, kg, bfr);

    lst[tid] = 0.f;
    __syncthreads();

    float s1[2] = {0.f, 0.f}, s2[2] = {0.f, 0.f};
    const int NT = NE / 64;
    for (int tile = blockIdx.x; tile < NT; tile += gridDim.x) {
        int e0 = tile * 64 + h * 32;
        long e = e0 + c;
        int i1 = idx1[e], i2 = idx2[e];
        f32x16 acc0, acc1;
        edge_mfma(x16, ef16, bfr, i1, i2, e, kg, acc0, acc1);
#pragma unroll
        for (int r = 0; r < 16; r++) {
            float v0 = acc0[r], v1 = acc1[r];
            s1[0] += v0; s2[0] += v0 * v0;
            s1[1] += v1; s2[1] += v1 * v1;
            if (STORE_Z) {
                int row = (r & 3) + 8 * (r >> 2) + 4 * kg;
                long ez = e0 + row;
                half2v p;
                p[0] = (f16)v0;  // gate col j = 32*ch+c
                p[1] = (f16)v1;  // conv col 64+j
                zp[ez * 64 + 32 * ch + c] = p;
            }
        }
    }
#pragma unroll
    for (int t = 0; t < 2; t++) {
        s1[t] += __shfl_xor(s1[t], 32, 64);
        s2[t] += __shfl_xor(s2[t], 32, 64);
    }
    if (kg == 0) {
#pragma unroll
        for (int t = 0; t < 2; t++) {
            int col = 32 * ch + 64 * t + c;
            atomicAdd(&lst[col], s1[t]);
            atomicAdd(&lst[128 + col], s2[t]);
        }
    }
    __syncthreads();
    atomicAdd(&estats[tid], lst[tid]);
}

// pass B (lean, streaming): read z pairs -> BN -> msg -> atomicAdd
__global__ __launch_bounds__(256) void k_edge_b_z(
    const half2v* __restrict__ zp, const int* __restrict__ idx1,
    const float* __restrict__ estats, const float* __restrict__ g1,
    const float* __restrict__ be1, float* __restrict__ nodesum) {
    long tid0 = (long)blockIdx.x * 256 + threadIdx.x;
    int j = (int)(tid0 & 63);  // grid stride is a multiple of 64 -> j fixed
    float mg = estats[j] * (1.f / NE);
    float vg = estats[128 + j] * (1.f / NE) - mg * mg;
    float ag = g1[j] * rsqrtf(vg + EPSB);
    float bg = be1[j] - mg * ag;
    float mc = estats[64 + j] * (1.f / NE);
    float vc = estats[192 + j] * (1.f / NE) - mc * mc;
    float ac = g1[64 + j] * rsqrtf(vc + EPSB);
    float bc = be1[64 + j] - mc * ac;
    long stride = (long)gridDim.x * 256;
    for (long idx = tid0; idx < (long)NE * 64; idx += stride) {
        long e = idx >> 6;
        half2v z = zp[idx];
        float g = fsigmoid((float)z[0] * ag + bg);
        float s = fsoftplus((float)z[1] * ac + bc);
        int n1 = idx1[e];
        atomicAdd(&nodesum[(size_t)n1 * 64 + j], g * s);
    }
}

// pass B fallback (recompute GEMM) if ws too small for zp
__global__ __launch_bounds__(256) void k_edge_b_g(
    const f16* __restrict__ x16, const f16* __restrict__ ef16,
    const f16* __restrict__ WT, const int* __restrict__ idx1,
    const int* __restrict__ idx2, const float* __restrict__ estats,
    const float* __restrict__ g1, const float* __restrict__ be1,
    float* __restrict__ nodesum) {
    int tid = threadIdx.x;
    int lane = tid & 63;
    int w = tid >> 6;
    int h = w >> 1, ch = w & 1;
    int c = lane & 31, kg = lane >> 5;

    float aC[2], bC[2];
#pragma unroll
    for (int t = 0; t < 2; t++) {
        int col = 32 * ch + 64 * t + c;
        float mean = estats[col] * (1.f / NE);
        float var = estats[128 + col] * (1.f / NE) - mean * mean;
        float rs = rsqrtf(var + EPSB);
        aC[t] = g1[col] * rs;
        bC[t] = be1[col] - mean * aC[t];
    }
    half8 bfr[2][12];
    load_bfr(WT, ch, c, kg, bfr);

    const int NT = NE / 64;
    for (int tile = blockIdx.x; tile < NT; tile += gridDim.x) {
        int e0 = tile * 64 + h * 32;
        long e = e0 + c;
        int i1 = idx1[e], i2 = idx2[e];
        f32x16 acc0, acc1;
        edge_mfma(x16, ef16, bfr, i1, i2, e, kg, acc0, acc1);
#pragma unroll
        for (int r = 0; r < 16; r++) {
            int row = (r & 3) + 8 * (r >> 2) + 4 * kg;
            int ez = e0 + row;
            float g = fsigmoid(acc0[r] * aC[0] + bC[0]);
            float sp = fsoftplus(acc1[r] * aC[1] + bC[1]);
            int node = idx1[ez];
            atomicAdd(&nodesum[node * 64 + 32 * ch + c], g * sp);
        }
    }
}

// ---------- node update ----------
__global__ __launch_bounds__(256) void k_node_stats(const float* __restrict__ nodesum,
                                                    const float* __restrict__ cnt1,
                                                    float* __restrict__ nstats) {
    __shared__ float lst[128];
    int tid = threadIdx.x;
    if (tid < 128) lst[tid] = 0.f;
    __syncthreads();
    int j = tid & 63;
    float p1 = 0.f, p2 = 0.f;
    for (int idx = blockIdx.x * 256 + tid; idx < NN * 64; idx += gridDim.x * 256) {
        int n = idx >> 6;
        float raw = nodesum[idx] / fmaxf(cnt1[n], 1.f);
        p1 += raw;
        p2 += raw * raw;
    }
    atomicAdd(&lst[j], p1);
    atomicAdd(&lst[64 + j], p2);
    __syncthreads();
    if (tid < 128) atomicAdd(&nstats[tid], lst[tid]);
}

__global__ __launch_bounds__(256) void k_node_apply(
    const float* __restrict__ nodesum, const float* __restrict__ cnt1,
    const float* __restrict__ nstats, const float* __restrict__ g2,
    const float* __restrict__ be2, float* __restrict__ xf, f16* __restrict__ x16) {
    for (int idx = blockIdx.x * blockDim.x + threadIdx.x; idx < NN * 64;
         idx += gridDim.x * blockDim.x) {
        int n = idx >> 6, j = idx & 63;
        float m = nstats[j] * (1.f / NN);
        float var = nstats[64 + j] * (1.f / NN) - m * m;
        float rs = rsqrtf(var + EPSB);
        float a = g2[j] * rs;
        float b = be2[j] - m * a;
        float raw = nodesum[idx] / fmaxf(cnt1[n], 1.f);
        float v = fsoftplus(xf[idx] + raw * a + b);
        xf[idx] = v;
        x16[idx] = (f16)v;
    }
}

// ---------- crystal pooling + MLP ----------
__global__ void k_cry(const float* __restrict__ xf, const int* __restrict__ idx3,
                      float* __restrict__ crsum) {
    for (int idx = blockIdx.x * blockDim.x + threadIdx.x; idx < NN * 64;
         idx += gridDim.x * blockDim.x) {
        int n = idx >> 6, j = idx & 63;
        atomicAdd(&crsum[idx3[n] * 64 + j], xf[idx]);
    }
}

__global__ __launch_bounds__(128) void k_out(const float* __restrict__ crsum,
                                             const float* __restrict__ cnt3,
                                             const float* __restrict__ Wc,
                                             const float* __restrict__ bcv,
                                             const float* __restrict__ Wo,
                                             const float* __restrict__ bo,
                                             float* __restrict__ out) {
    __shared__ float crym[64];
    __shared__ float red[4];
    int c = blockIdx.x, tid = threadIdx.x;
    if (tid < 64) crym[tid] = crsum[c * 64 + tid] / fmaxf(cnt3[c], 1.f);
    __syncthreads();
    float hv = bcv[tid];
#pragma unroll
    for (int k = 0; k < 64; k++) hv += crym[k] * Wc[k * 128 + tid];
    hv = fsoftplus(hv);
    float o0 = hv * Wo[tid * 2 + 0];
    float o1 = hv * Wo[tid * 2 + 1];
#pragma unroll
    for (int off = 32; off > 0; off >>= 1) {
        o0 += __shfl_down(o0, off, 64);
        o1 += __shfl_down(o1, off, 64);
    }
    int wv = tid >> 6;
    if ((tid & 63) == 0) { red[wv * 2] = o0; red[wv * 2 + 1] = o1; }
    __syncthreads();
    if (tid == 0) {
        out[c * 2 + 0] = red[0] + red[2] + bo[0];
        out[c * 2 + 1] = red[1] + red[3] + bo[1];
    }
}

// ---------- launch ----------
static inline size_t al256(size_t x) { return (x + 255) & ~(size_t)255; }

extern "C" void kernel_launch(void* const* d_in, const int* in_sizes, int n_in,
                              void* d_out, int out_size, void* d_ws, size_t ws_size,
                              hipStream_t stream) {
    const int* node_fea = (const int*)d_in[0];
    const float* edge_fea = (const float*)d_in[1];
    const int* idx1 = (const int*)d_in[2];
    const int* idx2 = (const int*)d_in[3];
    const int* idx3 = (const int*)d_in[4];
    const float* emb = (const float*)d_in[5];
    const float* Wf = (const float*)d_in[6];
    // d_in[7] = bf: cancels inside training-mode BN, unused.
    const float* g1 = (const float*)d_in[8];
    const float* be1 = (const float*)d_in[9];
    const float* g2 = (const float*)d_in[10];
    const float* be2 = (const float*)d_in[11];
    const float* Wc = (const float*)d_in[12];
    const float* bc = (const float*)d_in[13];
    const float* Wo = (const float*)d_in[14];
    const float* bo = (const float*)d_in[15];
    float* out = (float*)d_out;
    unsigned char* ws = (unsigned char*)d_ws;

    size_t off = 0;
    size_t o_xf = off;      off = al256(off + (size_t)NN * 64 * 4);
    size_t o_x16 = off;     off = al256(off + (size_t)NN * 64 * 2);
    size_t o_ef16 = off;    off = al256(off + (size_t)NE * 64 * 2);
    size_t o_WT = off;      off = al256(off + (size_t)128 * KPAD * 2);
    // prep-zero region:
    size_t o_cnt1 = off;    off = al256(off + (size_t)NN * 4);
    size_t o_cnt3 = off;    off = al256(off + (size_t)NC * 4);
    size_t o_crsum = off;   off = al256(off + (size_t)NC * 64 * 4);
    size_t prep_zero_end = off;
    // per-layer-zero region:
    size_t o_nodesum = off; off = al256(off + (size_t)NN * 64 * 4);
    size_t o_estats = off;  off = al256(off + 256 * 4);
    size_t o_nstats = off;  off = al256(off + 128 * 4);
    size_t layer_zero_end = off;
    size_t o_z = off;
    size_t need_z = o_z + (size_t)NE * 64 * 4;  // half2 per (edge, j)
    bool store_z = (ws_size >= need_z);

    float* xf = (float*)(ws + o_xf);
    f16* x16 = (f16*)(ws + o_x16);
    f16* ef16 = (f16*)(ws + o_ef16);
    f16* WT = (f16*)(ws + o_WT);
    float* cnt1 = (float*)(ws + o_cnt1);
    float* cnt3 = (float*)(ws + o_cnt3);
    float* crsum = (float*)(ws + o_crsum);
    float* nodesum = (float*)(ws + o_nodesum);
    float* estats = (float*)(ws + o_estats);
    float* nstats = (float*)(ws + o_nstats);
    half2v* zp = (half2v*)(ws + o_z);

    hipMemsetAsync(ws + o_cnt1, 0, prep_zero_end - o_cnt1, stream);
    k_prep_x<<<1024, 256, 0, stream>>>(node_fea, emb, xf, x16);
    k_prep_ef<<<4096, 256, 0, stream>>>(edge_fea, ef16);
    k_cnt<<<2048, 256, 0, stream>>>(idx1, idx3, cnt1, cnt3);

    for (int l = 0; l < 3; l++) {
        const float* Wf_l = Wf + (size_t)l * 169 * 128;
        hipMemsetAsync(ws + o_nodesum, 0, layer_zero_end - o_nodesum, stream);
        k_wt<<<96, 256, 0, stream>>>(Wf_l, WT);
        if (store_z) {
            k_edge_a<true><<<2048, 256, 0, stream>>>(x16, ef16, WT, idx1, idx2,
                                                     estats, zp);
            k_edge_b_z<<<4096, 256, 0, stream>>>(zp, idx1, estats, g1 + l * 128,
                                                 be1 + l * 128, nodesum);
        } else {
            k_edge_a<false><<<2048, 256, 0, stream>>>(x16, ef16, WT, idx1, idx2,
                                                      estats, zp);
            k_edge_b_g<<<2048, 256, 0, stream>>>(x16, ef16, WT, idx1, idx2, estats,
                                                 g1 + l * 128, be1 + l * 128, nodesum);
        }
        k_node_stats<<<1024, 256, 0, stream>>>(nodesum, cnt1, nstats);
        k_node_apply<<<1024, 256, 0, stream>>>(nodesum, cnt1, nstats, g2 + l * 64,
                                               be2 + l * 64, xf, x16);
    }
    k_cry<<<1024, 256, 0, stream>>>(xf, idx3, crsum);
    k_out<<<2000, 128, 0, stream>>>(crsum, cnt3, Wc, bc, Wo, bo, out);
}

// Round 4
// 1911.362 us; speedup vs baseline: 2.5291x; 1.2436x over previous
//
#include <hip/hip_runtime.h>
#include <hip/hip_bf16.h>

// CGCNN forward, MI355X. R3: CSR(idx1)-ordered z buffer.
//   prep: CSR build (deg/scan/scatter), ef16 gathered into CSR order (48-pad)
//   3x: pass A (CSR order): z = [x[i1]|x[i2]|ef] @ Wf[l] (f16 MFMA, fp32 acc;
//         bf cancels in train-mode BN) + column sum/sumsq + store z pairs
//       pass B: wave-per-node: read contiguous zp run -> BN -> sig*softplus ->
//         register reduce -> ONE plain store per node (no atomics) + node stats
//       node apply: BN2 -> softplus -> new x (last layer also crystal atomics)
//   crystal seg-mean -> softplus(@Wc+bc) -> @Wo+bo

#define NN 100000
#define NE 1600000
#define NC 2000
#define KPAD 176
#define EFW 48
#define EPSB 1e-5f
#define NCH 1000
#define CH 100

typedef _Float16 f16;
typedef _Float16 half8 __attribute__((ext_vector_type(8)));
typedef _Float16 half2v __attribute__((ext_vector_type(2)));
typedef float f32x16 __attribute__((ext_vector_type(16)));

__device__ __forceinline__ f32x16 zero16() {
    f32x16 v;
#pragma unroll
    for (int i = 0; i < 16; i++) v[i] = 0.f;
    return v;
}
__device__ __forceinline__ float fsoftplus(float x) {
    return fmaxf(x, 0.f) + __logf(1.f + __expf(-fabsf(x)));
}
__device__ __forceinline__ float fsigmoid(float x) {
    return __fdividef(1.f, 1.f + __expf(-x));
}

// ---------- prep ----------
__global__ void k_prep_x(const int* __restrict__ nf, const float* __restrict__ emb,
                         float* __restrict__ xf, f16* __restrict__ x16) {
    for (int idx = blockIdx.x * blockDim.x + threadIdx.x; idx < NN * 64;
         idx += gridDim.x * blockDim.x) {
        int n = idx >> 6, k = idx & 63;
        float v = emb[nf[n] * 64 + k];
        xf[idx] = v;
        x16[idx] = (f16)v;
    }
}

__global__ void k_deg(const int* __restrict__ idx1, const int* __restrict__ idx3,
                      int* deg1, float* cnt3) {
    for (int i = blockIdx.x * blockDim.x + threadIdx.x; i < NE;
         i += gridDim.x * blockDim.x) {
        atomicAdd(&deg1[idx1[i]], 1);
        if (i < NN) atomicAdd(&cnt3[idx3[i]], 1.f);
    }
}

// exclusive prefix sum of deg -> rp (NCH chunks of CH)
__global__ void k_scan_a(const int* __restrict__ deg, int* __restrict__ csum) {
    int t = blockIdx.x * blockDim.x + threadIdx.x;
    if (t < NCH) {
        int s = 0;
        int base = t * CH;
        for (int i = 0; i < CH; i++) s += deg[base + i];
        csum[t] = s;
    }
}
__global__ void k_scan_b(const int* __restrict__ csum, int* __restrict__ coff) {
    __shared__ int sc[256];
    int t = threadIdx.x;
    int v[4];
    int part = 0;
#pragma unroll
    for (int q = 0; q < 4; q++) {
        int idx = 4 * t + q;
        v[q] = (idx < NCH) ? csum[idx] : 0;
        part += v[q];
    }
    sc[t] = part;
    __syncthreads();
    for (int off = 1; off < 256; off <<= 1) {
        int add = (t >= off) ? sc[t - off] : 0;
        __syncthreads();
        sc[t] += add;
        __syncthreads();
    }
    int run = sc[t] - part;  // exclusive
#pragma unroll
    for (int q = 0; q < 4; q++) {
        int idx = 4 * t + q;
        if (idx < NCH) coff[idx] = run;
        run += v[q];
    }
}
__global__ void k_scan_c(const int* __restrict__ deg, const int* __restrict__ coff,
                         int* __restrict__ rp) {
    int t = blockIdx.x * blockDim.x + threadIdx.x;
    if (t < NCH) {
        int running = coff[t];
        int base = t * CH;
        for (int i = 0; i < CH; i++) {
            rp[base + i] = running;
            running += deg[base + i];
        }
    }
}

__global__ void k_scatter(const int* __restrict__ idx1, const int* __restrict__ idx2,
                          const int* __restrict__ rp1, int* cur1, int* elist1,
                          int* i1r, int* i2r) {
    for (int e = blockIdx.x * blockDim.x + threadIdx.x; e < NE;
         e += gridDim.x * blockDim.x) {
        int n1 = idx1[e];
        int p = rp1[n1] + atomicAdd(&cur1[n1], 1);
        elist1[p] = e;
        i1r[p] = n1;
        i2r[p] = idx2[e];
    }
}

// ef16p[p][0:48] = pad48(edge_fea[elist1[p]])  (CSR-permuted, f16)
__global__ void k_prep_efg(const float* __restrict__ ef, const int* __restrict__ elist1,
                           f16* __restrict__ ef16p) {
    for (long idx = (long)blockIdx.x * blockDim.x + threadIdx.x; idx < (long)NE * EFW;
         idx += (long)gridDim.x * blockDim.x) {
        long p = idx / EFW;
        int k = (int)(idx - p * EFW);
        int e = elist1[p];
        float v = (k < 41) ? ef[(size_t)e * 41 + k] : 0.f;
        ef16p[idx] = (f16)v;
    }
}

// WT[col][k] = Wf_l[k][col] (f16, k padded 169->176)
__global__ void k_wt(const float* __restrict__ Wf_l, f16* __restrict__ WT) {
    for (int idx = blockIdx.x * blockDim.x + threadIdx.x; idx < 128 * KPAD;
         idx += gridDim.x * blockDim.x) {
        int col = idx / KPAD, k = idx % KPAD;
        float v = (k < 169) ? Wf_l[k * 128 + col] : 0.f;
        WT[idx] = (f16)v;
    }
}

// ---------- pass A: CSR-ordered GEMM + stats + z store ----------
__global__ __launch_bounds__(256) void k_edge_a(
    const f16* __restrict__ x16, const f16* __restrict__ ef16p,
    const f16* __restrict__ WT, const int* __restrict__ i1r,
    const int* __restrict__ i2r, float* __restrict__ estats,
    half2v* __restrict__ zp) {
    __shared__ float lst[256];
    int tid = threadIdx.x;
    int lane = tid & 63;
    int w = tid >> 6;
    int h = w >> 1, ch = w & 1;
    int c = lane & 31, kg = lane >> 5;

    half8 bfr[2][11];
#pragma unroll
    for (int t = 0; t < 2; t++) {
        int col = 32 * ch + 64 * t + c;
        const f16* bp = WT + col * KPAD + kg * 8;
#pragma unroll
        for (int s = 0; s < 11; s++)
            bfr[t][s] = *reinterpret_cast<const half8*>(bp + s * 16);
    }

    lst[tid] = 0.f;
    __syncthreads();

    float s1[2] = {0.f, 0.f}, s2[2] = {0.f, 0.f};
    const int NT = NE / 64;
    for (int tile = blockIdx.x; tile < NT; tile += gridDim.x) {
        int p0 = tile * 64 + h * 32;
        long p = p0 + c;
        int i1 = i1r[p], i2 = i2r[p];
        f32x16 acc0 = zero16(), acc1 = zero16();
#pragma unroll
        for (int s = 0; s < 4; s++) {
            half8 a = *reinterpret_cast<const half8*>(x16 + (size_t)i1 * 64 + s * 16 + kg * 8);
            acc0 = __builtin_amdgcn_mfma_f32_32x32x16_f16(a, bfr[0][s], acc0, 0, 0, 0);
            acc1 = __builtin_amdgcn_mfma_f32_32x32x16_f16(a, bfr[1][s], acc1, 0, 0, 0);
        }
#pragma unroll
        for (int s = 0; s < 4; s++) {
            half8 a = *reinterpret_cast<const half8*>(x16 + (size_t)i2 * 64 + s * 16 + kg * 8);
            acc0 = __builtin_amdgcn_mfma_f32_32x32x16_f16(a, bfr[0][4 + s], acc0, 0, 0, 0);
            acc1 = __builtin_amdgcn_mfma_f32_32x32x16_f16(a, bfr[1][4 + s], acc1, 0, 0, 0);
        }
#pragma unroll
        for (int s = 0; s < 3; s++) {
            half8 a = *reinterpret_cast<const half8*>(ef16p + p * EFW + s * 16 + kg * 8);
            acc0 = __builtin_amdgcn_mfma_f32_32x32x16_f16(a, bfr[0][8 + s], acc0, 0, 0, 0);
            acc1 = __builtin_amdgcn_mfma_f32_32x32x16_f16(a, bfr[1][8 + s], acc1, 0, 0, 0);
        }
#pragma unroll
        for (int r = 0; r < 16; r++) {
            float v0 = acc0[r], v1 = acc1[r];
            s1[0] += v0; s2[0] += v0 * v0;
            s1[1] += v1; s2[1] += v1 * v1;
            int row = (r & 3) + 8 * (r >> 2) + 4 * kg;
            half2v pr;
            pr[0] = (f16)v0;  // gate col j = 32*ch+c
            pr[1] = (f16)v1;  // conv col 64+j
            zp[(size_t)(p0 + row) * 64 + 32 * ch + c] = pr;
        }
    }
#pragma unroll
    for (int t = 0; t < 2; t++) {
        s1[t] += __shfl_xor(s1[t], 32, 64);
        s2[t] += __shfl_xor(s2[t], 32, 64);
    }
    if (kg == 0) {
#pragma unroll
        for (int t = 0; t < 2; t++) {
            int col = 32 * ch + 64 * t + c;
            atomicAdd(&lst[col], s1[t]);
            atomicAdd(&lst[128 + col], s2[t]);
        }
    }
    __syncthreads();
    atomicAdd(&estats[tid], lst[tid]);
}

// ---------- pass B: wave-per-node reduce (no atomics on nodesum) ----------
__global__ __launch_bounds__(256) void k_nodered(
    const half2v* __restrict__ zp, const int* __restrict__ rp1,
    const int* __restrict__ deg1, const float* __restrict__ estats,
    const float* __restrict__ g1, const float* __restrict__ be1,
    float* __restrict__ raw_out, float* __restrict__ nstats) {
    __shared__ float sstat[128];
    int tid = threadIdx.x;
    int j = tid & 63, wv = tid >> 6;
    if (tid < 128) sstat[tid] = 0.f;
    __syncthreads();
    float mg = estats[j] * (1.f / NE);
    float vg = estats[128 + j] * (1.f / NE) - mg * mg;
    float ag = g1[j] * rsqrtf(vg + EPSB);
    float bg = be1[j] - mg * ag;
    float mc = estats[64 + j] * (1.f / NE);
    float vc = estats[192 + j] * (1.f / NE) - mc * mc;
    float ac = g1[64 + j] * rsqrtf(vc + EPSB);
    float bc = be1[64 + j] - mc * ac;
    float p1 = 0.f, p2 = 0.f;
    for (int n = blockIdx.x * 4 + wv; n < NN; n += gridDim.x * 4) {
        int st = rp1[n], d = deg1[n];
        float acc = 0.f;
        for (int q = 0; q < d; q++) {
            half2v z = zp[(size_t)(st + q) * 64 + j];
            float g = fsigmoid((float)z[0] * ag + bg);
            float s = fsoftplus((float)z[1] * ac + bc);
            acc += g * s;
        }
        float raw = acc / fmaxf((float)d, 1.f);
        raw_out[(size_t)n * 64 + j] = raw;
        p1 += raw;
        p2 += raw * raw;
    }
    atomicAdd(&sstat[j], p1);
    atomicAdd(&sstat[64 + j], p2);
    __syncthreads();
    if (tid < 128) atomicAdd(&nstats[tid], sstat[tid]);
}

// ---------- node apply: BN2 + softplus (+ crystal pool on last layer) ----------
template <bool LAST>
__global__ __launch_bounds__(256) void k_node_apply(
    const float* __restrict__ raw_in, const float* __restrict__ nstats,
    const float* __restrict__ g2, const float* __restrict__ be2,
    float* __restrict__ xf, f16* __restrict__ x16, const int* __restrict__ idx3,
    float* __restrict__ crsum) {
    for (int idx = blockIdx.x * blockDim.x + threadIdx.x; idx < NN * 64;
         idx += gridDim.x * blockDim.x) {
        int n = idx >> 6, j = idx & 63;
        float m = nstats[j] * (1.f / NN);
        float var = nstats[64 + j] * (1.f / NN) - m * m;
        float rs = rsqrtf(var + EPSB);
        float a = g2[j] * rs;
        float b = be2[j] - m * a;
        float v = fsoftplus(xf[idx] + raw_in[idx] * a + b);
        if (LAST) {
            atomicAdd(&crsum[(size_t)idx3[n] * 64 + j], v);
        } else {
            xf[idx] = v;
            x16[idx] = (f16)v;
        }
    }
}

// ---------- output MLP ----------
__global__ __launch_bounds__(128) void k_out(const float* __restrict__ crsum,
                                             const float* __restrict__ cnt3,
                                             const float* __restrict__ Wc,
                                             const float* __restrict__ bcv,
                                             const float* __restrict__ Wo,
                                             const float* __restrict__ bo,
                                             float* __restrict__ out) {
    __shared__ float crym[64];
    __shared__ float red[4];
    int c = blockIdx.x, tid = threadIdx.x;
    if (tid < 64) crym[tid] = crsum[c * 64 + tid] / fmaxf(cnt3[c], 1.f);
    __syncthreads();
    float hv = bcv[tid];
#pragma unroll
    for (int k = 0; k < 64; k++) hv += crym[k] * Wc[k * 128 + tid];
    hv = fsoftplus(hv);
    float o0 = hv * Wo[tid * 2 + 0];
    float o1 = hv * Wo[tid * 2 + 1];
#pragma unroll
    for (int off = 32; off > 0; off >>= 1) {
        o0 += __shfl_down(o0, off, 64);
        o1 += __shfl_down(o1, off, 64);
    }
    int wv = tid >> 6;
    if ((tid & 63) == 0) { red[wv * 2] = o0; red[wv * 2 + 1] = o1; }
    __syncthreads();
    if (tid == 0) {
        out[c * 2 + 0] = red[0] + red[2] + bo[0];
        out[c * 2 + 1] = red[1] + red[3] + bo[1];
    }
}

// ---------- launch ----------
static inline size_t al256(size_t x) { return (x + 255) & ~(size_t)255; }

extern "C" void kernel_launch(void* const* d_in, const int* in_sizes, int n_in,
                              void* d_out, int out_size, void* d_ws, size_t ws_size,
                              hipStream_t stream) {
    const int* node_fea = (const int*)d_in[0];
    const float* edge_fea = (const float*)d_in[1];
    const int* idx1 = (const int*)d_in[2];
    const int* idx2 = (const int*)d_in[3];
    const int* idx3 = (const int*)d_in[4];
    const float* emb = (const float*)d_in[5];
    const float* Wf = (const float*)d_in[6];
    // d_in[7] = bf: cancels inside training-mode BN, unused.
    const float* g1 = (const float*)d_in[8];
    const float* be1 = (const float*)d_in[9];
    const float* g2 = (const float*)d_in[10];
    const float* be2 = (const float*)d_in[11];
    const float* Wc = (const float*)d_in[12];
    const float* bc = (const float*)d_in[13];
    const float* Wo = (const float*)d_in[14];
    const float* bo = (const float*)d_in[15];
    float* out = (float*)d_out;
    unsigned char* ws = (unsigned char*)d_ws;

    size_t off = 0;
    size_t o_xf = off;     off = al256(off + (size_t)NN * 64 * 4);
    size_t o_x16 = off;    off = al256(off + (size_t)NN * 64 * 2);
    size_t o_efp = off;    off = al256(off + (size_t)NE * EFW * 2);
    size_t o_WT = off;     off = al256(off + (size_t)128 * KPAD * 2);
    size_t o_rp1 = off;    off = al256(off + (size_t)NN * 4);
    size_t o_el1 = off;    off = al256(off + (size_t)NE * 4);
    size_t o_i1r = off;    off = al256(off + (size_t)NE * 4);
    size_t o_i2r = off;    off = al256(off + (size_t)NE * 4);
    size_t o_raw = off;    off = al256(off + (size_t)NN * 64 * 4);
    // prep-zero region (one memset):
    size_t o_deg1 = off;   off = al256(off + (size_t)NN * 4);
    size_t o_cur1 = off;   off = al256(off + (size_t)NN * 4);
    size_t o_cnt3 = off;   off = al256(off + (size_t)NC * 4);
    size_t o_csum = off;   off = al256(off + 1024 * 4);
    size_t o_coff = off;   off = al256(off + 1024 * 4);
    size_t o_crsum = off;  off = al256(off + (size_t)NC * 64 * 4);
    size_t prep_zero_end = off;
    // per-layer-zero region (tiny memset per layer):
    size_t o_estats = off; off = al256(off + 256 * 4);
    size_t o_nstats = off; off = al256(off + 128 * 4);
    size_t layer_zero_end = off;
    size_t o_z = off;      off = al256(off + (size_t)NE * 64 * 4);
    (void)ws_size;  // ~648 MB total; R2's 680 MB layout fit.

    float* xf = (float*)(ws + o_xf);
    f16* x16 = (f16*)(ws + o_x16);
    f16* ef16p = (f16*)(ws + o_efp);
    f16* WT = (f16*)(ws + o_WT);
    int* rp1 = (int*)(ws + o_rp1);
    int* elist1 = (int*)(ws + o_el1);
    int* i1r = (int*)(ws + o_i1r);
    int* i2r = (int*)(ws + o_i2r);
    float* raw = (float*)(ws + o_raw);
    int* deg1 = (int*)(ws + o_deg1);
    int* cur1 = (int*)(ws + o_cur1);
    float* cnt3 = (float*)(ws + o_cnt3);
    int* csum = (int*)(ws + o_csum);
    int* coff = (int*)(ws + o_coff);
    float* crsum = (float*)(ws + o_crsum);
    float* estats = (float*)(ws + o_estats);
    float* nstats = (float*)(ws + o_nstats);
    half2v* zp = (half2v*)(ws + o_z);

    hipMemsetAsync(ws + o_deg1, 0, prep_zero_end - o_deg1, stream);
    k_prep_x<<<1024, 256, 0, stream>>>(node_fea, emb, xf, x16);
    k_deg<<<2048, 256, 0, stream>>>(idx1, idx3, deg1, cnt3);
    k_scan_a<<<4, 256, 0, stream>>>(deg1, csum);
    k_scan_b<<<1, 256, 0, stream>>>(csum, coff);
    k_scan_c<<<4, 256, 0, stream>>>(deg1, coff, rp1);
    k_scatter<<<2048, 256, 0, stream>>>(idx1, idx2, rp1, cur1, elist1, i1r, i2r);
    k_prep_efg<<<4096, 256, 0, stream>>>(edge_fea, elist1, ef16p);

    for (int l = 0; l < 3; l++) {
        const float* Wf_l = Wf + (size_t)l * 169 * 128;
        hipMemsetAsync(ws + o_estats, 0, layer_zero_end - o_estats, stream);
        k_wt<<<88, 256, 0, stream>>>(Wf_l, WT);
        k_edge_a<<<2048, 256, 0, stream>>>(x16, ef16p, WT, i1r, i2r, estats, zp);
        k_nodered<<<4096, 256, 0, stream>>>(zp, rp1, deg1, estats, g1 + l * 128,
                                            be1 + l * 128, raw, nstats);
        if (l < 2) {
            k_node_apply<false><<<1024, 256, 0, stream>>>(raw, nstats, g2 + l * 64,
                                                          be2 + l * 64, xf, x16,
                                                          idx3, crsum);
        } else {
            k_node_apply<true><<<1024, 256, 0, stream>>>(raw, nstats, g2 + l * 64,
                                                         be2 + l * 64, xf, x16,
                                                         idx3, crsum);
        }
    }
    k_out<<<2000, 128, 0, stream>>>(crsum, cnt3, Wc, bc, Wo, bo, out);
}

// Round 5
// 1820.259 us; speedup vs baseline: 2.6557x; 1.0500x over previous
//
#include <hip/hip_runtime.h>
#include <hip/hip_bf16.h>

// CGCNN forward, MI355X. R4: R3 structure; pass A rewritten for occupancy
// (1 acc/wave, 4 waves share an edge tile; was 2 acc + 124 VGPR -> 21% occ).
//   prep: CSR build (deg/scan/scatter), ef16 gathered into CSR order (48-pad)
//   3x: pass A (CSR order): z = [x[i1]|x[i2]|ef] @ Wf[l] (f16 MFMA, fp32 acc;
//         bf cancels in train-mode BN) + column sum/sumsq + store z pairs
//       pass B: wave-per-node: read contiguous zp run -> BN -> sig*softplus ->
//         register reduce -> ONE plain store per node (no atomics) + node stats
//       node apply: BN2 -> softplus -> new x (last layer also crystal atomics)
//   crystal seg-mean -> softplus(@Wc+bc) -> @Wo+bo

#define NN 100000
#define NE 1600000
#define NC 2000
#define KPAD 176
#define EFW 48
#define EPSB 1e-5f
#define NCH 1000
#define CH 100

typedef _Float16 f16;
typedef _Float16 half8 __attribute__((ext_vector_type(8)));
typedef _Float16 half2v __attribute__((ext_vector_type(2)));
typedef float f32x16 __attribute__((ext_vector_type(16)));

__device__ __forceinline__ f32x16 zero16() {
    f32x16 v;
#pragma unroll
    for (int i = 0; i < 16; i++) v[i] = 0.f;
    return v;
}
__device__ __forceinline__ float fsoftplus(float x) {
    return fmaxf(x, 0.f) + __logf(1.f + __expf(-fabsf(x)));
}
__device__ __forceinline__ float fsigmoid(float x) {
    return __fdividef(1.f, 1.f + __expf(-x));
}

// ---------- prep ----------
__global__ void k_prep_x(const int* __restrict__ nf, const float* __restrict__ emb,
                         float* __restrict__ xf, f16* __restrict__ x16) {
    for (int idx = blockIdx.x * blockDim.x + threadIdx.x; idx < NN * 64;
         idx += gridDim.x * blockDim.x) {
        int n = idx >> 6, k = idx & 63;
        float v = emb[nf[n] * 64 + k];
        xf[idx] = v;
        x16[idx] = (f16)v;
    }
}

__global__ void k_deg(const int* __restrict__ idx1, const int* __restrict__ idx3,
                      int* deg1, float* cnt3) {
    for (int i = blockIdx.x * blockDim.x + threadIdx.x; i < NE;
         i += gridDim.x * blockDim.x) {
        atomicAdd(&deg1[idx1[i]], 1);
        if (i < NN) atomicAdd(&cnt3[idx3[i]], 1.f);
    }
}

// exclusive prefix sum of deg -> rp (NCH chunks of CH)
__global__ void k_scan_a(const int* __restrict__ deg, int* __restrict__ csum) {
    int t = blockIdx.x * blockDim.x + threadIdx.x;
    if (t < NCH) {
        int s = 0;
        int base = t * CH;
        for (int i = 0; i < CH; i++) s += deg[base + i];
        csum[t] = s;
    }
}
__global__ void k_scan_b(const int* __restrict__ csum, int* __restrict__ coff) {
    __shared__ int sc[256];
    int t = threadIdx.x;
    int v[4];
    int part = 0;
#pragma unroll
    for (int q = 0; q < 4; q++) {
        int idx = 4 * t + q;
        v[q] = (idx < NCH) ? csum[idx] : 0;
        part += v[q];
    }
    sc[t] = part;
    __syncthreads();
    for (int off = 1; off < 256; off <<= 1) {
        int add = (t >= off) ? sc[t - off] : 0;
        __syncthreads();
        sc[t] += add;
        __syncthreads();
    }
    int run = sc[t] - part;  // exclusive
#pragma unroll
    for (int q = 0; q < 4; q++) {
        int idx = 4 * t + q;
        if (idx < NCH) coff[idx] = run;
        run += v[q];
    }
}
__global__ void k_scan_c(const int* __restrict__ deg, const int* __restrict__ coff,
                         int* __restrict__ rp) {
    int t = blockIdx.x * blockDim.x + threadIdx.x;
    if (t < NCH) {
        int running = coff[t];
        int base = t * CH;
        for (int i = 0; i < CH; i++) {
            rp[base + i] = running;
            running += deg[base + i];
        }
    }
}

__global__ void k_scatter(const int* __restrict__ idx1, const int* __restrict__ idx2,
                          const int* __restrict__ rp1, int* cur1, int* elist1,
                          int* i1r, int* i2r) {
    for (int e = blockIdx.x * blockDim.x + threadIdx.x; e < NE;
         e += gridDim.x * blockDim.x) {
        int n1 = idx1[e];
        int p = rp1[n1] + atomicAdd(&cur1[n1], 1);
        elist1[p] = e;
        i1r[p] = n1;
        i2r[p] = idx2[e];
    }
}

// ef16p[p][0:48] = pad48(edge_fea[elist1[p]])  (CSR-permuted, f16)
__global__ void k_prep_efg(const float* __restrict__ ef, const int* __restrict__ elist1,
                           f16* __restrict__ ef16p) {
    for (long idx = (long)blockIdx.x * blockDim.x + threadIdx.x; idx < (long)NE * EFW;
         idx += (long)gridDim.x * blockDim.x) {
        long p = idx / EFW;
        int k = (int)(idx - p * EFW);
        int e = elist1[p];
        float v = (k < 41) ? ef[(size_t)e * 41 + k] : 0.f;
        ef16p[idx] = (f16)v;
    }
}

// WT[col][k] = Wf_l[k][col] (f16, k padded 169->176)
__global__ void k_wt(const float* __restrict__ Wf_l, f16* __restrict__ WT) {
    for (int idx = blockIdx.x * blockDim.x + threadIdx.x; idx < 128 * KPAD;
         idx += gridDim.x * blockDim.x) {
        int col = idx / KPAD, k = idx % KPAD;
        float v = (k < 169) ? Wf_l[k * 128 + col] : 0.f;
        WT[idx] = (f16)v;
    }
}

// ---------- pass A: CSR-ordered GEMM + stats + z store ----------
// Block = 4 waves sharing one 32-edge tile; wave q owns cols 32q..32q+31
// (1 acc + 11 B-frags per wave => ~90 VGPR => 5-6 waves/SIMD vs R3's 124/21%).
// Redundant i1/i2/x16/ef loads across the 4 waves hit L1 (same addresses).
__global__ __launch_bounds__(256) void k_edge_a(
    const f16* __restrict__ x16, const f16* __restrict__ ef16p,
    const f16* __restrict__ WT, const int* __restrict__ i1r,
    const int* __restrict__ i2r, float* __restrict__ estats,
    f16* __restrict__ zph) {
    __shared__ float lst[256];
    int tid = threadIdx.x;
    int lane = tid & 63;
    int q = tid >> 6;
    int c = lane & 31, kg = lane >> 5;
    int col = 32 * q + c;

    half8 bfr[11];
    {
        const f16* bp = WT + col * KPAD + kg * 8;
#pragma unroll
        for (int s = 0; s < 11; s++)
            bfr[s] = *reinterpret_cast<const half8*>(bp + s * 16);
    }
    // z layout consumed by k_nodered: f16 pair {gate j, conv j} at p*128+2j
    const size_t zoff = 2 * (size_t)(col & 63) + (col >> 6);

    float s1 = 0.f, s2 = 0.f;
    const int NT = NE / 32;
    for (int tile = blockIdx.x; tile < NT; tile += gridDim.x) {
        int p0 = tile * 32;
        long p = p0 + c;
        int i1 = i1r[p], i2 = i2r[p];
        f32x16 acc = zero16();
#pragma unroll
        for (int s = 0; s < 4; s++) {
            half8 a = *reinterpret_cast<const half8*>(x16 + (size_t)i1 * 64 + s * 16 + kg * 8);
            acc = __builtin_amdgcn_mfma_f32_32x32x16_f16(a, bfr[s], acc, 0, 0, 0);
        }
#pragma unroll
        for (int s = 0; s < 4; s++) {
            half8 a = *reinterpret_cast<const half8*>(x16 + (size_t)i2 * 64 + s * 16 + kg * 8);
            acc = __builtin_amdgcn_mfma_f32_32x32x16_f16(a, bfr[4 + s], acc, 0, 0, 0);
        }
#pragma unroll
        for (int s = 0; s < 3; s++) {
            half8 a = *reinterpret_cast<const half8*>(ef16p + p * EFW + s * 16 + kg * 8);
            acc = __builtin_amdgcn_mfma_f32_32x32x16_f16(a, bfr[8 + s], acc, 0, 0, 0);
        }
#pragma unroll
        for (int r = 0; r < 16; r++) {
            float v = acc[r];
            s1 += v;
            s2 += v * v;
            int row = (r & 3) + 8 * (r >> 2) + 4 * kg;
            __builtin_nontemporal_store((f16)v, &zph[(size_t)(p0 + row) * 128 + zoff]);
        }
    }
    s1 += __shfl_xor(s1, 32, 64);
    s2 += __shfl_xor(s2, 32, 64);
    if (kg == 0) {
        lst[col] = s1;        // each col slot written by exactly one lane
        lst[128 + col] = s2;
    }
    __syncthreads();
    atomicAdd(&estats[tid], lst[tid]);
}

// ---------- pass B: wave-per-node reduce (no atomics on nodesum) ----------
__global__ __launch_bounds__(256) void k_nodered(
    const half2v* __restrict__ zp, const int* __restrict__ rp1,
    const int* __restrict__ deg1, const float* __restrict__ estats,
    const float* __restrict__ g1, const float* __restrict__ be1,
    float* __restrict__ raw_out, float* __restrict__ nstats) {
    __shared__ float sstat[128];
    int tid = threadIdx.x;
    int j = tid & 63, wv = tid >> 6;
    if (tid < 128) sstat[tid] = 0.f;
    __syncthreads();
    float mg = estats[j] * (1.f / NE);
    float vg = estats[128 + j] * (1.f / NE) - mg * mg;
    float ag = g1[j] * rsqrtf(vg + EPSB);
    float bg = be1[j] - mg * ag;
    float mc = estats[64 + j] * (1.f / NE);
    float vc = estats[192 + j] * (1.f / NE) - mc * mc;
    float ac = g1[64 + j] * rsqrtf(vc + EPSB);
    float bc = be1[64 + j] - mc * ac;
    float p1 = 0.f, p2 = 0.f;
    for (int n = blockIdx.x * 4 + wv; n < NN; n += gridDim.x * 4) {
        int st = rp1[n], d = deg1[n];
        float acc = 0.f;
#pragma unroll 4
        for (int q = 0; q < d; q++) {
            half2v z = __builtin_nontemporal_load(&zp[(size_t)(st + q) * 64 + j]);
            float g = fsigmoid((float)z[0] * ag + bg);
            float s = fsoftplus((float)z[1] * ac + bc);
            acc += g * s;
        }
        float raw = acc / fmaxf((float)d, 1.f);
        raw_out[(size_t)n * 64 + j] = raw;
        p1 += raw;
        p2 += raw * raw;
    }
    atomicAdd(&sstat[j], p1);
    atomicAdd(&sstat[64 + j], p2);
    __syncthreads();
    if (tid < 128) atomicAdd(&nstats[tid], sstat[tid]);
}

// ---------- node apply: BN2 + softplus (+ crystal pool on last layer) ----------
template <bool LAST>
__global__ __launch_bounds__(256) void k_node_apply(
    const float* __restrict__ raw_in, const float* __restrict__ nstats,
    const float* __restrict__ g2, const float* __restrict__ be2,
    float* __restrict__ xf, f16* __restrict__ x16, const int* __restrict__ idx3,
    float* __restrict__ crsum) {
    for (int idx = blockIdx.x * blockDim.x + threadIdx.x; idx < NN * 64;
         idx += gridDim.x * blockDim.x) {
        int n = idx >> 6, j = idx & 63;
        float m = nstats[j] * (1.f / NN);
        float var = nstats[64 + j] * (1.f / NN) - m * m;
        float rs = rsqrtf(var + EPSB);
        float a = g2[j] * rs;
        float b = be2[j] - m * a;
        float v = fsoftplus(xf[idx] + raw_in[idx] * a + b);
        if (LAST) {
            atomicAdd(&crsum[(size_t)idx3[n] * 64 + j], v);
        } else {
            xf[idx] = v;
            x16[idx] = (f16)v;
        }
    }
}

// ---------- output MLP ----------
__global__ __launch_bounds__(128) void k_out(const float* __restrict__ crsum,
                                             const float* __restrict__ cnt3,
                                             const float* __restrict__ Wc,
                                             const float* __restrict__ bcv,
                                             const float* __restrict__ Wo,
                                             const float* __restrict__ bo,
                                             float* __restrict__ out) {
    __shared__ float crym[64];
    __shared__ float red[4];
    int c = blockIdx.x, tid = threadIdx.x;
    if (tid < 64) crym[tid] = crsum[c * 64 + tid] / fmaxf(cnt3[c], 1.f);
    __syncthreads();
    float hv = bcv[tid];
#pragma unroll
    for (int k = 0; k < 64; k++) hv += crym[k] * Wc[k * 128 + tid];
    hv = fsoftplus(hv);
    float o0 = hv * Wo[tid * 2 + 0];
    float o1 = hv * Wo[tid * 2 + 1];
#pragma unroll
    for (int off = 32; off > 0; off >>= 1) {
        o0 += __shfl_down(o0, off, 64);
        o1 += __shfl_down(o1, off, 64);
    }
    int wv = tid >> 6;
    if ((tid & 63) == 0) { red[wv * 2] = o0; red[wv * 2 + 1] = o1; }
    __syncthreads();
    if (tid == 0) {
        out[c * 2 + 0] = red[0] + red[2] + bo[0];
        out[c * 2 + 1] = red[1] + red[3] + bo[1];
    }
}

// ---------- launch ----------
static inline size_t al256(size_t x) { return (x + 255) & ~(size_t)255; }

extern "C" void kernel_launch(void* const* d_in, const int* in_sizes, int n_in,
                              void* d_out, int out_size, void* d_ws, size_t ws_size,
                              hipStream_t stream) {
    const int* node_fea = (const int*)d_in[0];
    const float* edge_fea = (const float*)d_in[1];
    const int* idx1 = (const int*)d_in[2];
    const int* idx2 = (const int*)d_in[3];
    const int* idx3 = (const int*)d_in[4];
    const float* emb = (const float*)d_in[5];
    const float* Wf = (const float*)d_in[6];
    // d_in[7] = bf: cancels inside training-mode BN, unused.
    const float* g1 = (const float*)d_in[8];
    const float* be1 = (const float*)d_in[9];
    const float* g2 = (const float*)d_in[10];
    const float* be2 = (const float*)d_in[11];
    const float* Wc = (const float*)d_in[12];
    const float* bc = (const float*)d_in[13];
    const float* Wo = (const float*)d_in[14];
    const float* bo = (const float*)d_in[15];
    float* out = (float*)d_out;
    unsigned char* ws = (unsigned char*)d_ws;

    size_t off = 0;
    size_t o_xf = off;     off = al256(off + (size_t)NN * 64 * 4);
    size_t o_x16 = off;    off = al256(off + (size_t)NN * 64 * 2);
    size_t o_efp = off;    off = al256(off + (size_t)NE * EFW * 2);
    size_t o_WT = off;     off = al256(off + (size_t)128 * KPAD * 2);
    size_t o_rp1 = off;    off = al256(off + (size_t)NN * 4);
    size_t o_el1 = off;    off = al256(off + (size_t)NE * 4);
    size_t o_i1r = off;    off = al256(off + (size_t)NE * 4);
    size_t o_i2r = off;    off = al256(off + (size_t)NE * 4);
    size_t o_raw = off;    off = al256(off + (size_t)NN * 64 * 4);
    // prep-zero region (one memset):
    size_t o_deg1 = off;   off = al256(off + (size_t)NN * 4);
    size_t o_cur1 = off;   off = al256(off + (size_t)NN * 4);
    size_t o_cnt3 = off;   off = al256(off + (size_t)NC * 4);
    size_t o_csum = off;   off = al256(off + 1024 * 4);
    size_t o_coff = off;   off = al256(off + 1024 * 4);
    size_t o_crsum = off;  off = al256(off + (size_t)NC * 64 * 4);
    size_t prep_zero_end = off;
    // per-layer-zero region (tiny memset per layer):
    size_t o_estats = off; off = al256(off + 256 * 4);
    size_t o_nstats = off; off = al256(off + 128 * 4);
    size_t layer_zero_end = off;
    size_t o_z = off;      off = al256(off + (size_t)NE * 64 * 4);
    (void)ws_size;

    float* xf = (float*)(ws + o_xf);
    f16* x16 = (f16*)(ws + o_x16);
    f16* ef16p = (f16*)(ws + o_efp);
    f16* WT = (f16*)(ws + o_WT);
    int* rp1 = (int*)(ws + o_rp1);
    int* elist1 = (int*)(ws + o_el1);
    int* i1r = (int*)(ws + o_i1r);
    int* i2r = (int*)(ws + o_i2r);
    float* raw = (float*)(ws + o_raw);
    int* deg1 = (int*)(ws + o_deg1);
    int* cur1 = (int*)(ws + o_cur1);
    float* cnt3 = (float*)(ws + o_cnt3);
    int* csum = (int*)(ws + o_csum);
    int* coff = (int*)(ws + o_coff);
    float* crsum = (float*)(ws + o_crsum);
    float* estats = (float*)(ws + o_estats);
    float* nstats = (float*)(ws + o_nstats);
    f16* zph = (f16*)(ws + o_z);
    half2v* zp = (half2v*)(ws + o_z);

    hipMemsetAsync(ws + o_deg1, 0, prep_zero_end - o_deg1, stream);
    k_prep_x<<<1024, 256, 0, stream>>>(node_fea, emb, xf, x16);
    k_deg<<<2048, 256, 0, stream>>>(idx1, idx3, deg1, cnt3);
    k_scan_a<<<4, 256, 0, stream>>>(deg1, csum);
    k_scan_b<<<1, 256, 0, stream>>>(csum, coff);
    k_scan_c<<<4, 256, 0, stream>>>(deg1, coff, rp1);
    k_scatter<<<2048, 256, 0, stream>>>(idx1, idx2, rp1, cur1, elist1, i1r, i2r);
    k_prep_efg<<<4096, 256, 0, stream>>>(edge_fea, elist1, ef16p);

    for (int l = 0; l < 3; l++) {
        const float* Wf_l = Wf + (size_t)l * 169 * 128;
        hipMemsetAsync(ws + o_estats, 0, layer_zero_end - o_estats, stream);
        k_wt<<<88, 256, 0, stream>>>(Wf_l, WT);
        k_edge_a<<<4096, 256, 0, stream>>>(x16, ef16p, WT, i1r, i2r, estats, zph);
        k_nodered<<<4096, 256, 0, stream>>>(zp, rp1, deg1, estats, g1 + l * 128,
                                            be1 + l * 128, raw, nstats);
        if (l < 2) {
            k_node_apply<false><<<1024, 256, 0, stream>>>(raw, nstats, g2 + l * 64,
                                                          be2 + l * 64, xf, x16,
                                                          idx3, crsum);
        } else {
            k_node_apply<true><<<1024, 256, 0, stream>>>(raw, nstats, g2 + l * 64,
                                                         be2 + l * 64, xf, x16,
                                                         idx3, crsum);
        }
    }
    k_out<<<2000, 128, 0, stream>>>(crsum, cnt3, Wc, bc, Wo, bo, out);
}